// Round 6
// baseline (627.178 us; speedup 1.0000x reference)
//
#include <hip/hip_runtime.h>
#include <math.h>

// ---------------------------------------------------------------------------
// AttnBlock: per-edge radial-MLP attention logits + segment softmax over dst.
//
// Structure (3 stream ops):
//   memset ssum[N]=0 (double)
//   K1 edge:  dot[e] -> d_out (fp32), atomicAdd ssum[v[e]] += exp((double)dot)
//   K2 norm:  d_out[e] = (float)( exp((double)dot) / ssum[v[e]] )
//
// fp64 exp/sum/divide replaces the per-node max pass: exp range +-709 in
// double strictly dominates the achievable |dot| (LN bounds the MLP output).
//
// R9 (this round): PERSISTENT BLOCKS + ASYNC-STAGE PIPELINE (T14).
//   Evidence: VALU-busy time pinned at ~78us across 5 structures; stall is
//   phase-structural (per-slab cold-start: gathers + wj staging + s_load
//   warmup, serialized behind a barrier, all waves stalled together).
//   R8 proved in-lane ILP can't fill it; R2 proved occupancy can't either.
//   Fix: persistent blocks loop over slabs; slab i+1's global loads are
//   issued into REGISTERS before slab i's compute (HBM latency hides under
//   the ~0.4us trunk), written to LDS after the barrier. Cold-start paid
//   once per block (~8 slabs), not per slab. Weights stay K$-warm.
//   - Trunk = R7's proven wave-per-MLP edge-pair f2 (unchanged math).
//   - sprep SoA (R8's win: bank conflicts 3.3M -> 0).
//   - All per-edge wj (incl. wj00) in one flat f4-slot stage array.
//   - Epilogue distributed: 128 threads, coalesced out[] write, fp64
//     exp+atomic spread over 2 waves. sv double-buffered (only LDS region
//     read concurrently with next-slab staging writes).
// ---------------------------------------------------------------------------

#define TPB 256
#define EPB 128
// float offsets inside the staged slab (f4 slot layout):
//   s11: slots [0,864)    = floats [0,3456)      (128 edges x 27)
//   s01: slots [864,960)  = floats [3456,3840)   (128 x 3)
//   s10: slots [960,1056) = floats [3840,4224)   (128 x 3)
//   s00: slots [1056,1088)= floats [4224,4352)   (128 x 1)
#define S01F 3456
#define S10F 3840
#define S00F 4224
#define NSLOT 1088

typedef float f2 __attribute__((ext_vector_type(2)));
typedef float f4 __attribute__((ext_vector_type(4)));

static __device__ __forceinline__ f2 fma2(f2 a, f2 b, f2 c) {
    return __builtin_elementwise_fma(a, b, c);
}
static __device__ __forceinline__ f2 splat(float x) {
    f2 r;
    r.x = x;
    r.y = x;
    return r;
}
static __device__ __forceinline__ f2 mk2(float a, float b) {
    f2 r;
    r.x = a;
    r.y = b;
    return r;
}

// guarded f4 load: full vector when wholly in-bounds, else per-element
static __device__ __forceinline__ f4 ldf4g(const float* __restrict__ p,
                                           long fb, long lim) {
    f4 r;
    if (fb + 4 <= lim) {
        r = *(const f4*)(p + fb);
    } else {
        r.x = (fb + 0 < lim) ? p[fb + 0] : 0.f;
        r.y = (fb + 1 < lim) ? p[fb + 1] : 0.f;
        r.z = (fb + 2 < lim) ? p[fb + 2] : 0.f;
        r.w = (fb + 3 < lim) ? p[fb + 3] : 0.f;
    }
    return r;
}

// LayerNorm(16)+ReLU, edge-pair packed: h[c] = {edgeA ch c, edgeB ch c}.
static __device__ __forceinline__ void ln_relu_pair(f2* h,
                                                    const float* __restrict__ g,
                                                    const float* __restrict__ be) {
    f2 s = ((h[0] + h[1]) + (h[2] + h[3])) + ((h[4] + h[5]) + (h[6] + h[7])) +
           (((h[8] + h[9]) + (h[10] + h[11])) +
            ((h[12] + h[13]) + (h[14] + h[15])));
    const f2 mu = s * splat(0.0625f);
    f2 vs = splat(0.f);
#pragma unroll
    for (int c = 0; c < 16; ++c) {
        f2 d = h[c] - mu;
        vs = fma2(d, d, vs);
    }
    const f2 var = vs * splat(0.0625f);
    f2 r;
    r.x = rsqrtf(var.x + 1e-5f);
    r.y = rsqrtf(var.y + 1e-5f);
    const f2 zero = splat(0.f);
#pragma unroll
    for (int c = 0; c < 16; ++c) {
        f2 t = (h[c] - mu) * r;
        h[c] = __builtin_elementwise_max(fma2(t, splat(g[c]), splat(be[c])), zero);
    }
}

// layers 1..2 of a radial MLP, edge-pair packed: vec(3)->16->LN/relu->16->LN/relu
static __device__ __forceinline__ void radial_pair(
    f2 v0, f2 v1, f2 v2, const float* __restrict__ W1,
    const float* __restrict__ b1, const float* __restrict__ g1,
    const float* __restrict__ be1, const float* __restrict__ W2,
    const float* __restrict__ b2, const float* __restrict__ g2,
    const float* __restrict__ be2, f2* h2) {
    f2 h[16];
#pragma unroll
    for (int c = 0; c < 16; ++c)
        h[c] = fma2(v0, splat(W1[c]),
                    fma2(v1, splat(W1[16 + c]),
                         fma2(v2, splat(W1[32 + c]), splat(b1[c]))));
    ln_relu_pair(h, g1, be1);

#pragma unroll
    for (int c2 = 0; c2 < 16; ++c2) h2[c2] = splat(b2[c2]);
#pragma unroll
    for (int c = 0; c < 16; ++c) {
#pragma unroll
        for (int c2 = 0; c2 < 16; ++c2)
            h2[c2] = fma2(h[c], splat(W2[c * 16 + c2]), h2[c2]);
    }
    ln_relu_pair(h2, g2, be2);
}

// layer3 (OUT=4), edge-pair packed: p[oi] for oi = o*2+i
static __device__ __forceinline__ void layer3_pair4(const f2* h2,
                                                    const float* __restrict__ W3,
                                                    const float* __restrict__ b3,
                                                    f2 p[4]) {
#pragma unroll
    for (int oi = 0; oi < 4; ++oi) p[oi] = splat(b3[oi]);
#pragma unroll
    for (int c = 0; c < 16; ++c) {
#pragma unroll
        for (int oi = 0; oi < 4; ++oi)
            p[oi] = fma2(h2[c], splat(W3[c * 4 + oi]), p[oi]);
    }
}

// registers holding one slab's staged data (issued early, written late: T14)
struct SReg {
    f4 a0, a1, a2, a3, ax;
    float pp[11];
    int vv;
};

static __device__ __forceinline__ void load_stage(
    int S, int E, int tid, const float* __restrict__ f0,
    const float* __restrict__ f1, const float* __restrict__ dist,
    const int* __restrict__ u, const int* __restrict__ v,
    const float* __restrict__ wj00, const float* __restrict__ wj01,
    const float* __restrict__ wj10, const float* __restrict__ wj11, SReg& r) {
    const long sb = (long)S * EPB;
    const long lim11 = (long)E * 27;
    const long lim3 = (long)E * 3;
    const long b11 = sb * 27;
    const long b3 = sb * 3;
    r.a0 = ldf4g(wj11, b11 + 4L * tid, lim11);
    r.a1 = ldf4g(wj11, b11 + 4L * (tid + 256), lim11);
    r.a2 = ldf4g(wj11, b11 + 4L * (tid + 512), lim11);
    {
        const int s3 = tid + 768;
        if (s3 < 864)
            r.a3 = ldf4g(wj11, b11 + 4L * s3, lim11);
        else if (s3 < 960)
            r.a3 = ldf4g(wj01, b3 + 4L * (s3 - 864), lim3);
        else
            r.a3 = ldf4g(wj10, b3 + 4L * (s3 - 960), lim3);
    }
    if (tid < 64) {
        const int sx = 1024 + tid;
        if (sx < 1056)
            r.ax = ldf4g(wj10, b3 + 4L * (sx - 960), lim3);
        else
            r.ax = ldf4g(wj00, sb + 4L * (sx - 1056), (long)E);
    }
    if (tid >= 128) {
        const int t = tid - 128;
        const long e = sb + t;
        r.vv = 0;
#pragma unroll
        for (int k = 0; k < 11; ++k) r.pp[k] = 0.f;
        if (e < E) {
            const int uu = u[e];
            r.vv = v[e];
            const f2 f0u = *(const f2*)(f0 + (size_t)uu * 2);
            const f2 f0vv = *(const f2*)(f0 + (size_t)r.vv * 2);
            const f2 f1a = *(const f2*)(f1 + (size_t)r.vv * 6);
            const f2 f1b = *(const f2*)(f1 + (size_t)r.vv * 6 + 2);
            const f2 f1c = *(const f2*)(f1 + (size_t)r.vv * 6 + 4);
            r.pp[0] = f0u.x * f0vv.x;  // vec0
            r.pp[1] = f0u.y * f0vv.y;  // vec1
            r.pp[2] = dist[e];         // vec2
            r.pp[3] = f0vv.x;          // f0v0
            r.pp[4] = f0vv.y;          // f0v1
            r.pp[5] = f1a.x;           // f1v[0][0]
            r.pp[6] = f1a.y;           // f1v[0][1]
            r.pp[7] = f1b.x;           // f1v[0][2]
            r.pp[8] = f1b.y;           // f1v[1][0]
            r.pp[9] = f1c.x;           // f1v[1][1]
            r.pp[10] = f1c.y;          // f1v[1][2]
        }
    }
}

__global__ __launch_bounds__(TPB, 4) void edge_kernel(
    const float* __restrict__ f0, const float* __restrict__ f1,
    const float* __restrict__ dist, const int* __restrict__ u,
    const int* __restrict__ v, const float* __restrict__ wq,
    const float* __restrict__ wj00, const float* __restrict__ wj01,
    const float* __restrict__ wj10, const float* __restrict__ wj11,
    const float* __restrict__ rW1, const float* __restrict__ rb1,
    const float* __restrict__ g1, const float* __restrict__ be1,
    const float* __restrict__ rW2, const float* __restrict__ rb2,
    const float* __restrict__ g2, const float* __restrict__ be2,
    const float* __restrict__ W3_00, const float* __restrict__ b3_00,
    const float* __restrict__ W3_01, const float* __restrict__ b3_01,
    const float* __restrict__ W3_10, const float* __restrict__ b3_10,
    const float* __restrict__ W3_11, const float* __restrict__ b3_11,
    float* __restrict__ out, double* __restrict__ ssum, int E) {
    __shared__ __align__(16) f4 sstage[NSLOT];
    __shared__ float sprep[11][EPB];  // SoA: conflict-free both sides
    __shared__ int sv[2][EPB];        // double-buffered (epilogue overlap)
    __shared__ float pdotf[4][EPB];

    const int tid = threadIdx.x;
    float* __restrict__ sf = (float*)sstage;
    const int nslab = (E + EPB - 1) / EPB;

    int s = blockIdx.x;  // grid is clamped to nslab at launch
    SReg r;
    load_stage(s, E, tid, f0, f1, dist, u, v, wj00, wj01, wj10, wj11, r);
    int par = 0;

    while (s < nslab) {
        // ---- write staged regs -> LDS (waitcnt auto-inserted here) ----
        sstage[tid] = r.a0;
        sstage[tid + 256] = r.a1;
        sstage[tid + 512] = r.a2;
        sstage[tid + 768] = r.a3;
        if (tid < 64) sstage[1024 + tid] = r.ax;
        if (tid >= 128) {
            const int t = tid - 128;
#pragma unroll
            for (int k = 0; k < 11; ++k) sprep[k][t] = r.pp[k];
            sv[par][t] = r.vv;
        }
        __syncthreads();

        // ---- issue next slab's loads EARLY (latency hides under trunk) ----
        const int snext = s + (int)gridDim.x;
        if (snext < nslab)
            load_stage(snext, E, tid, f0, f1, dist, u, v, wj00, wj01, wj10,
                       wj11, r);

        // ---- compute (R7 trunk, unchanged math) ----
        const int l = tid & 63;
        const int w = __builtin_amdgcn_readfirstlane(tid >> 6);

        const f2 vec0 = mk2(sprep[0][l], sprep[0][l + 64]);
        const f2 vec1 = mk2(sprep[1][l], sprep[1][l + 64]);
        const f2 vec2 = mk2(sprep[2][l], sprep[2][l + 64]);

        f2 h2[16];
        radial_pair(vec0, vec1, vec2, rW1 + w * 48, rb1 + w * 16, g1 + w * 16,
                    be1 + w * 16, rW2 + w * 256, rb2 + w * 16, g2 + w * 16,
                    be2 + w * 16, h2);

        const f2 f0v0 = mk2(sprep[3][l], sprep[3][l + 64]);
        const f2 f0v1 = mk2(sprep[4][l], sprep[4][l + 64]);
        f2 f1v[2][3];
        if (w != 0) {
            f1v[0][0] = mk2(sprep[5][l], sprep[5][l + 64]);
            f1v[0][1] = mk2(sprep[6][l], sprep[6][l + 64]);
            f1v[0][2] = mk2(sprep[7][l], sprep[7][l + 64]);
            f1v[1][0] = mk2(sprep[8][l], sprep[8][l + 64]);
            f1v[1][1] = mk2(sprep[9][l], sprep[9][l + 64]);
            f1v[1][2] = mk2(sprep[10][l], sprep[10][l + 64]);
        }

        f2 dotp = splat(0.f);
        if (w == 0) {  // (l=0,k=0)
            f2 p[4];
            layer3_pair4(h2, W3_00, b3_00, p);
            const f2 wj = mk2(sf[S00F + l], sf[S00F + l + 64]);
            const f2 a0 = wj * fma2(p[0], f0v0, p[1] * f0v1);
            const f2 a1 = wj * fma2(p[2], f0v0, p[3] * f0v1);
            const f2 q00 = fma2(splat(wq[0]), f0v0, splat(wq[1]) * f0v1);
            const f2 q01 = fma2(splat(wq[2]), f0v0, splat(wq[3]) * f0v1);
            dotp = fma2(q00, a0, q01 * a1);
        } else if (w == 1) {  // (l=0,k=1)
            f2 p[4];
            layer3_pair4(h2, W3_01, b3_01, p);
            const float* mA = sf + S01F + l * 3;
            const float* mB = sf + S01F + (l + 64) * 3;
            f2 s0 = splat(0.f), s1 = splat(0.f);
#pragma unroll
            for (int m = 0; m < 3; ++m) {
                const f2 wm = mk2(mA[m], mB[m]);
                s0 = fma2(wm, f1v[0][m], s0);
                s1 = fma2(wm, f1v[1][m], s1);
            }
            const f2 a0 = fma2(p[0], s0, p[1] * s1);
            const f2 a1 = fma2(p[2], s0, p[3] * s1);
            const f2 q00 = fma2(splat(wq[0]), f0v0, splat(wq[1]) * f0v1);
            const f2 q01 = fma2(splat(wq[2]), f0v0, splat(wq[3]) * f0v1);
            dotp = fma2(q00, a0, q01 * a1);
        } else if (w == 2) {  // (l=1,k=0)
            f2 p[4];
            layer3_pair4(h2, W3_10, b3_10, p);
            const f2 t0 = fma2(p[0], f0v0, p[1] * f0v1);
            const f2 t1 = fma2(p[2], f0v0, p[3] * f0v1);
            const float* mA = sf + S10F + l * 3;
            const float* mB = sf + S10F + (l + 64) * 3;
#pragma unroll
            for (int m = 0; m < 3; ++m) {
                const f2 wm = mk2(mA[m], mB[m]);
                const f2 q0 =
                    fma2(splat(wq[4]), f1v[0][m], splat(wq[5]) * f1v[1][m]);
                const f2 q1 =
                    fma2(splat(wq[6]), f1v[0][m], splat(wq[7]) * f1v[1][m]);
                dotp = fma2(q0 * wm, t0, dotp);
                dotp = fma2(q1 * wm, t1, dotp);
            }
        } else {  // (l=1,k=1)
            f2 p[3][4];
#pragma unroll
            for (int j = 0; j < 3; ++j)
#pragma unroll
                for (int oi = 0; oi < 4; ++oi)
                    p[j][oi] = splat(b3_11[j * 4 + oi]);
#pragma unroll
            for (int c = 0; c < 16; ++c) {
#pragma unroll
                for (int j = 0; j < 3; ++j)
#pragma unroll
                    for (int oi = 0; oi < 4; ++oi)
                        p[j][oi] = fma2(h2[c],
                                        splat(W3_11[c * 12 + j * 4 + oi]),
                                        p[j][oi]);
            }
            const float* mA = sf + l * 27;
            const float* mB = sf + (l + 64) * 27;
            f2 acc1[2][3];
#pragma unroll
            for (int m = 0; m < 3; ++m) {
                acc1[0][m] = splat(0.f);
                acc1[1][m] = splat(0.f);
            }
#pragma unroll
            for (int j = 0; j < 3; ++j) {
#pragma unroll
                for (int m = 0; m < 3; ++m) {
                    const f2 w0 =
                        mk2(mA[j * 9 + m * 3 + 0], mB[j * 9 + m * 3 + 0]);
                    const f2 w1 =
                        mk2(mA[j * 9 + m * 3 + 1], mB[j * 9 + m * 3 + 1]);
                    const f2 w2 =
                        mk2(mA[j * 9 + m * 3 + 2], mB[j * 9 + m * 3 + 2]);
                    const f2 B0 =
                        fma2(w0, f1v[0][0], fma2(w1, f1v[0][1], w2 * f1v[0][2]));
                    const f2 B1 =
                        fma2(w0, f1v[1][0], fma2(w1, f1v[1][1], w2 * f1v[1][2]));
                    acc1[0][m] = fma2(p[j][0], B0, fma2(p[j][1], B1, acc1[0][m]));
                    acc1[1][m] = fma2(p[j][2], B0, fma2(p[j][3], B1, acc1[1][m]));
                }
            }
#pragma unroll
            for (int m = 0; m < 3; ++m) {
                const f2 q0 =
                    fma2(splat(wq[4]), f1v[0][m], splat(wq[5]) * f1v[1][m]);
                const f2 q1 =
                    fma2(splat(wq[6]), f1v[0][m], splat(wq[7]) * f1v[1][m]);
                dotp = fma2(q0, acc1[0][m], dotp);
                dotp = fma2(q1, acc1[1][m], dotp);
            }
        }

        pdotf[w][l] = dotp.x;
        pdotf[w][l + 64] = dotp.y;
        __syncthreads();

        // ---- distributed epilogue: coalesced out, fp64 exp over 2 waves ----
        if (tid < EPB) {
            const long e = (long)s * EPB + tid;
            if (e < E) {
                const float dsum = pdotf[0][tid] + pdotf[1][tid] +
                                   pdotf[2][tid] + pdotf[3][tid];
                out[e] = dsum;
                atomicAdd(&ssum[sv[par][tid]], exp((double)dsum));
            }
        }
        s = snext;
        par ^= 1;
    }
}

__global__ void norm_kernel(float* __restrict__ out, const int* __restrict__ v,
                            const double* __restrict__ ssum, int E) {
    int e = blockIdx.x * blockDim.x + threadIdx.x;
    if (e >= E) return;
    const double t = exp((double)out[e]);
    out[e] = (float)(t / ssum[v[e]]);
}

extern "C" void kernel_launch(void* const* d_in, const int* in_sizes, int n_in,
                              void* d_out, int out_size, void* d_ws,
                              size_t ws_size, hipStream_t stream) {
    const float* f0 = (const float*)d_in[0];
    const float* f1 = (const float*)d_in[1];
    const float* dist = (const float*)d_in[2];
    const int* u = (const int*)d_in[3];
    const int* v = (const int*)d_in[4];
    const float* wq = (const float*)d_in[5];
    const float* wj00 = (const float*)d_in[6];
    const float* wj01 = (const float*)d_in[7];
    const float* wj10 = (const float*)d_in[8];
    const float* wj11 = (const float*)d_in[9];
    const float* rW1 = (const float*)d_in[10];
    const float* rb1 = (const float*)d_in[11];
    const float* g1 = (const float*)d_in[12];
    const float* be1 = (const float*)d_in[13];
    const float* rW2 = (const float*)d_in[14];
    const float* rb2 = (const float*)d_in[15];
    const float* g2 = (const float*)d_in[16];
    const float* be2 = (const float*)d_in[17];
    const float* W3_00 = (const float*)d_in[18];
    const float* b3_00 = (const float*)d_in[19];
    const float* W3_01 = (const float*)d_in[20];
    const float* b3_01 = (const float*)d_in[21];
    const float* W3_10 = (const float*)d_in[22];
    const float* b3_10 = (const float*)d_in[23];
    const float* W3_11 = (const float*)d_in[24];
    const float* b3_11 = (const float*)d_in[25];

    const int N = in_sizes[0] / 2;  // f0 is [N,2,1]
    const int E = in_sizes[2];      // dist is [E]

    double* ssum = (double*)d_ws;
    float* out = (float*)d_out;

    hipMemsetAsync(ssum, 0, (size_t)N * sizeof(double), stream);
    const int nslab = (E + EPB - 1) / EPB;
    const int ge = nslab < 1536 ? nslab : 1536;  // 256 CU x 6 blocks/CU
    edge_kernel<<<ge, TPB, 0, stream>>>(
        f0, f1, dist, u, v, wq, wj00, wj01, wj10, wj11, rW1, rb1, g1, be1, rW2,
        rb2, g2, be2, W3_00, b3_00, W3_01, b3_01, W3_10, b3_10, W3_11, b3_11,
        out, ssum, E);
    const int gn = (E + 255) / 256;
    norm_kernel<<<gn, 256, 0, stream>>>(out, v, ssum, E);
}